// Round 7
// baseline (1200.644 us; speedup 1.0000x reference)
//
#include <hip/hip_runtime.h>

#define NB   16
#define NPC  4096
#define MPC  1024
#define KNB  64
#define FIN  64
#define CAP  448   // candidate capacity per centroid (mean ~137, +26 sigma)

typedef unsigned short u16;
typedef unsigned int   u32;
typedef unsigned long long u64;
typedef __attribute__((ext_vector_type(8))) short short8;
typedef __attribute__((ext_vector_type(4))) float f32x4;

__device__ __forceinline__ u16 f2bf(float f) {
  u32 u = __float_as_uint(f);
  u = u + 0x7fffu + ((u >> 16) & 1u);
  return (u16)(u >> 16);
}
__device__ __forceinline__ float bf2f(u16 b) {
  return __uint_as_float(((u32)b) << 16);
}

// ---- DPP wave reduces (VALU pipe). Canonical 6-stage chain; result lane 63.
// bound_ctrl=false => masked/invalid lanes keep old; compiler inserts the
// mandatory DPP hazard waits (raw asm version faulted in R2).
#define DPP64_MAX(best, ctrl, rmask) do { \
  u32 _lo = (u32)(best), _hi = (u32)((best) >> 32); \
  u32 _olo = (u32)__builtin_amdgcn_update_dpp((int)_lo, (int)_lo, (ctrl), (rmask), 0xf, false); \
  u32 _ohi = (u32)__builtin_amdgcn_update_dpp((int)_hi, (int)_hi, (ctrl), (rmask), 0xf, false); \
  u64 _o = ((u64)_ohi << 32) | _olo; \
  (best) = _o > (best) ? _o : (best); \
} while (0)

#define DPP64_MAX_ALL(k) do { \
  DPP64_MAX(k, 0x111, 0xf); DPP64_MAX(k, 0x112, 0xf); \
  DPP64_MAX(k, 0x114, 0xf); DPP64_MAX(k, 0x118, 0xf); \
  DPP64_MAX(k, 0x142, 0xa); DPP64_MAX(k, 0x143, 0xc); \
} while (0)

__device__ __forceinline__ u32 wave_max_u32(u32 x) {
  u32 t;
  t = (u32)__builtin_amdgcn_update_dpp((int)x, (int)x, 0x111, 0xf, 0xf, false); x = x > t ? x : t;
  t = (u32)__builtin_amdgcn_update_dpp((int)x, (int)x, 0x112, 0xf, 0xf, false); x = x > t ? x : t;
  t = (u32)__builtin_amdgcn_update_dpp((int)x, (int)x, 0x114, 0xf, 0xf, false); x = x > t ? x : t;
  t = (u32)__builtin_amdgcn_update_dpp((int)x, (int)x, 0x118, 0xf, 0xf, false); x = x > t ? x : t;
  t = (u32)__builtin_amdgcn_update_dpp((int)x, (int)x, 0x142, 0xa, 0xf, false); x = x > t ? x : t;
  t = (u32)__builtin_amdgcn_update_dpp((int)x, (int)x, 0x143, 0xc, 0xf, false); x = x > t ? x : t;
  return x;
}
__device__ __forceinline__ u32 wave_min_u32(u32 x) {
  u32 t;
  t = (u32)__builtin_amdgcn_update_dpp((int)x, (int)x, 0x111, 0xf, 0xf, false); x = x < t ? x : t;
  t = (u32)__builtin_amdgcn_update_dpp((int)x, (int)x, 0x112, 0xf, 0xf, false); x = x < t ? x : t;
  t = (u32)__builtin_amdgcn_update_dpp((int)x, (int)x, 0x114, 0xf, 0xf, false); x = x < t ? x : t;
  t = (u32)__builtin_amdgcn_update_dpp((int)x, (int)x, 0x118, 0xf, 0xf, false); x = x < t ? x : t;
  t = (u32)__builtin_amdgcn_update_dpp((int)x, (int)x, 0x142, 0xa, 0xf, false); x = x < t ? x : t;
  t = (u32)__builtin_amdgcn_update_dpp((int)x, (int)x, 0x143, 0xc, 0xf, false); x = x < t ? x : t;
  return x;
}

// 4x4x4 Morton cell (coords in [0,1))
__device__ __forceinline__ int cell_of(float x, float y, float z) {
  int ix = (int)(x * 4.f); ix = ix < 0 ? 0 : (ix > 3 ? 3 : ix);
  int iy = (int)(y * 4.f); iy = iy < 0 ? 0 : (iy > 3 ? 3 : iy);
  int iz = (int)(z * 4.f); iz = iz < 0 ? 0 : (iz > 3 ? 3 : iz);
  return (ix & 1) | ((iy & 1) << 1) | ((iz & 1) << 2)
       | ((ix >> 1) << 3) | ((iy >> 1) << 4) | ((iz >> 1) << 5);
}

// ---------------------------------------------------------------- FPS
// One block (512 thr = 8 waves) per cloud. Wave-owned Morton bucket of 512
// pts (8/lane), register-resident state. The winner's COORDINATES ride the
// reduction slots, so no step ever does a dependent sx[last] LDS fetch,
// and the skip path touches LDS only at the post-barrier scan.
// Skip test: dist2(c,bbox)*0.999 >= wave max mind => fminf identity =>
// bit-exact no-op. Distance math: __f*_rn, (x2+y2)+z2, fminf. Argmax
// first-index tie-break exact via (mindbits<<32)|~origidx u64 max
// (indices unique => keys unique). Single barrier per step.
__global__ __launch_bounds__(512)
void fps_kernel(const float* __restrict__ pos, int* __restrict__ idx_out,
                float* __restrict__ pos_out, float* __restrict__ batch_out) {
  const int b = blockIdx.x;
  const int t = threadIdx.x;
  const int w = t >> 6, lane = t & 63;
  const float* P = pos + (size_t)b * NPC * 3;
  __shared__ float sx[NPC], sy[NPC], sz[NPC];   // ORIG-indexed (setup only)
  __shared__ int   slist[NPC];                  // sorted -> orig
  __shared__ int   hist[64], cellbase[64];
  __shared__ u64   skey[2][8];                  // per-wave key, parity-dbuf
  __shared__ float4 scds[2][8];                 // per-wave winner coords
  for (int i = t; i < NPC; i += 512) {
    sx[i] = P[3*i+0]; sy[i] = P[3*i+1]; sz[i] = P[3*i+2];
  }
  for (int i = t; i < MPC; i += 512) batch_out[b*MPC + i] = (float)b;
  if (t < 64) hist[t] = 0;
  __syncthreads();
  for (int p = t; p < NPC; p += 512)
    atomicAdd(&hist[cell_of(sx[p], sy[p], sz[p])], 1);
  __syncthreads();
  if (t == 0) {
    int run = 0;
    for (int c = 0; c < 64; ++c) { cellbase[c] = run; run += hist[c]; }
  }
  __syncthreads();
  if (t < 64) hist[t] = 0;
  __syncthreads();
  for (int p = t; p < NPC; p += 512) {
    int c = cell_of(sx[p], sy[p], sz[p]);
    int r = cellbase[c] + atomicAdd(&hist[c], 1);
    slist[r] = p;     // intra-cell order nondeterministic: affects only
  }                   // bucket membership => skip pattern, never values
  __syncthreads();
  // wave w owns sorted chunk [512w, 512w+512): 8 pts/lane
  float px[8], py[8], pz[8], mind[8];
  u32 noi[8];
#pragma unroll
  for (int j = 0; j < 8; ++j) {
    int s = (w << 9) + (j << 6) + lane;
    int o = slist[s];
    noi[j] = ~(u32)o;
    px[j] = sx[o]; py[j] = sy[o]; pz[j] = sz[o];
    mind[j] = __builtin_inff();
  }
  // wave bbox -> uniform registers (coords >= 0 so u32 cmp == f32 cmp)
  float mnx = px[0], mxx = px[0], mny = py[0], mxy = py[0], mnz = pz[0], mxz = pz[0];
#pragma unroll
  for (int j = 1; j < 8; ++j) {
    mnx = fminf(mnx, px[j]); mxx = fmaxf(mxx, px[j]);
    mny = fminf(mny, py[j]); mxy = fmaxf(mxy, py[j]);
    mnz = fminf(mnz, pz[j]); mxz = fmaxf(mxz, pz[j]);
  }
  const float blox = __uint_as_float(__builtin_amdgcn_readlane((int)wave_min_u32(__float_as_uint(mnx)), 63));
  const float bhix = __uint_as_float(__builtin_amdgcn_readlane((int)wave_max_u32(__float_as_uint(mxx)), 63));
  const float bloy = __uint_as_float(__builtin_amdgcn_readlane((int)wave_min_u32(__float_as_uint(mny)), 63));
  const float bhiy = __uint_as_float(__builtin_amdgcn_readlane((int)wave_max_u32(__float_as_uint(mxy)), 63));
  const float bloz = __uint_as_float(__builtin_amdgcn_readlane((int)wave_min_u32(__float_as_uint(mnz)), 63));
  const float bhiz = __uint_as_float(__builtin_amdgcn_readlane((int)wave_max_u32(__float_as_uint(mxz)), 63));
  // wave state: running max key; +inf value => step 1 updates all waves
  u32 wk_hi = 0x7f800000u, wk_lo = 0u;
  // current centroid (registers; from scan after step 1)
  float cx = sx[0], cy = sy[0], cz = sz[0];
  if (t == 0) {
    idx_out[b*MPC] = 0;
    pos_out[(size_t)b*MPC*3 + 0] = cx;
    pos_out[(size_t)b*MPC*3 + 1] = cy;
    pos_out[(size_t)b*MPC*3 + 2] = cz;
  }
  __syncthreads();
  for (int m = 1; m < MPC; ++m) {
    const int pr = m & 1;
    // early non-blocking read: this wave's previous slot coords (own write,
    // barrier-separated => no race); used only on the skip path
    float4 pvc = scds[pr ^ 1][w];
    float t0 = fmaxf(fmaxf(blox - cx, cx - bhix), 0.f);
    float t1 = fmaxf(fmaxf(bloy - cy, cy - bhiy), 0.f);
    float t2 = fmaxf(fmaxf(bloz - cz, cz - bhiz), 0.f);
    float bound = (t0*t0 + t1*t1) + t2*t2;
    if (bound * 0.999f < __uint_as_float(wk_hi)) {   // wave-uniform branch
      u64 kk = 0;
#pragma unroll
      for (int j = 0; j < 8; ++j) {
        float dx = __fsub_rn(px[j], cx);
        float dy = __fsub_rn(py[j], cy);
        float dz = __fsub_rn(pz[j], cz);
        float d2 = __fadd_rn(__fadd_rn(__fmul_rn(dx,dx), __fmul_rn(dy,dy)), __fmul_rn(dz,dz));
        mind[j] = fminf(mind[j], d2);
        u64 key = ((u64)__float_as_uint(mind[j]) << 32) | noi[j];
        kk = key > kk ? key : kk;
      }
      DPP64_MAX_ALL(kk);             // result lane 63
      wk_lo = (u32)__builtin_amdgcn_readlane((int)(u32)kk, 63);
      wk_hi = (u32)__builtin_amdgcn_readlane((int)(u32)(kk >> 32), 63);
      // owner lane (unique noi match) publishes winner coords (exact bits)
      bool own = false; float ox = 0.f, oy = 0.f, oz = 0.f;
#pragma unroll
      for (int j = 0; j < 8; ++j) {
        bool o = (noi[j] == wk_lo);
        own |= o;
        ox = o ? px[j] : ox; oy = o ? py[j] : oy; oz = o ? pz[j] : oz;
      }
      if (own) scds[pr][w] = make_float4(ox, oy, oz, 0.f);
      if (lane == 0) skey[pr][w] = ((u64)wk_hi << 32) | wk_lo;
    } else {
      if (lane == 0) {
        skey[pr][w] = ((u64)wk_hi << 32) | wk_lo;
        scds[pr][w] = pvc;           // carry winner coords forward
      }
    }
    __syncthreads();   // single barrier per step (parity double-buffer)
    // scan: max-merge 8 (key, coords) slots — coords ride along, so no
    // dependent sx[last] fetch afterwards
    u64 k0 = skey[pr][0], k1 = skey[pr][1], k2 = skey[pr][2], k3 = skey[pr][3];
    u64 k4 = skey[pr][4], k5 = skey[pr][5], k6 = skey[pr][6], k7 = skey[pr][7];
    float4 c0 = scds[pr][0], c1 = scds[pr][1], c2 = scds[pr][2], c3 = scds[pr][3];
    float4 c4 = scds[pr][4], c5 = scds[pr][5], c6 = scds[pr][6], c7 = scds[pr][7];
    if (k1 > k0) { k0 = k1; c0 = c1; }
    if (k3 > k2) { k2 = k3; c2 = c3; }
    if (k5 > k4) { k4 = k5; c4 = c5; }
    if (k7 > k6) { k6 = k7; c6 = c7; }
    if (k2 > k0) { k0 = k2; c0 = c2; }
    if (k6 > k4) { k4 = k6; c4 = c6; }
    if (k4 > k0) { k0 = k4; c0 = c4; }
    cx = c0.x; cy = c0.y; cz = c0.z;
    if (t == 0) {
      int last = (int)(~(u32)k0);
      idx_out[b*MPC + m] = last;
      size_t po = ((size_t)b*MPC + m)*3;
      pos_out[po+0] = cx; pos_out[po+1] = cy; pos_out[po+2] = cz;
    }
  }
}

// ---------------------------------------------------------------- y = x @ W1[:64]  (f32 accum, bf16 store)
__global__ __launch_bounds__(256)
void y_kernel(const float* __restrict__ x, const float* __restrict__ w1,
              u16* __restrict__ y) {
  __shared__ float xs[64][68];
  __shared__ float ws[64][68];
  const int t = threadIdx.x;
  const size_t row0 = (size_t)blockIdx.x * 64;
#pragma unroll
  for (int k = 0; k < 4; ++k) {
    int l = t + 256*k;               // 0..1023 float4 index
    int r = l >> 4, c4 = l & 15;
    *(float4*)&xs[r][c4*4] = *(const float4*)&x[(row0 + r)*64 + c4*4];
    *(float4*)&ws[r][c4*4] = *(const float4*)&w1[r*64 + c4*4];
  }
  __syncthreads();
  const int r = t >> 2, c0 = (t & 3) << 4;
  float acc[16];
#pragma unroll
  for (int i = 0; i < 16; ++i) acc[i] = 0.f;
  for (int k = 0; k < 64; ++k) {
    float a = xs[r][k];
#pragma unroll
    for (int j = 0; j < 4; ++j) {
      float4 wv = *(const float4*)&ws[k][c0 + 4*j];
      acc[4*j+0] += a * wv.x; acc[4*j+1] += a * wv.y;
      acc[4*j+2] += a * wv.z; acc[4*j+3] += a * wv.w;
    }
  }
  u32 u[8];
#pragma unroll
  for (int i = 0; i < 8; ++i)
    u[i] = (u32)f2bf(acc[2*i]) | ((u32)f2bf(acc[2*i+1]) << 16);
  u16* dst = y + ((row0 + r)*64 + c0);
  ((uint4*)dst)[0] = make_uint4(u[0],u[1],u[2],u[3]);
  ((uint4*)dst)[1] = make_uint4(u[4],u[5],u[6],u[7]);
}

// ---------------------------------------------------------------- W2 -> bf16 transposed [128][64]
__global__ __launch_bounds__(256)
void w2t_kernel(const float* __restrict__ w2, u16* __restrict__ w2t) {
  int t = blockIdx.x*256 + threadIdx.x;
  if (t < 64*128) {
    int k = t >> 7, c = t & 127;
    w2t[c*64 + k] = f2bf(w2[t]);
  }
}

// ---------------------------------------------------------------- radius + top-64 neighbors
// Replicates lax.top_k(-d2,64) stability via key=(d2_bits, idx) ranking.
__global__ __launch_bounds__(256)
void nbr_kernel(const float* __restrict__ pos, const int* __restrict__ idx,
                int* __restrict__ nbr, int* __restrict__ nvalid) {
  const int bid = blockIdx.x;
  const int sw = (bid & 7) * 512 + (bid >> 3);   // bijective XCD swizzle (4096 = 8*512)
  const int cloud = sw >> 8;
  const int mbase = (sw & 255) << 2;
  __shared__ float sx[NPC], sy[NPC], sz[NPC];
  __shared__ u64 cand[4][CAP];
  const float* P = pos + (size_t)cloud * NPC * 3;
  const int t = threadIdx.x;
  for (int i = t; i < NPC; i += 256) { sx[i]=P[3*i]; sy[i]=P[3*i+1]; sz[i]=P[3*i+2]; }
  __syncthreads();
  const int wv = t >> 6, lane = t & 63;
  const int m = mbase + wv;
  const int g = cloud * MPC + m;
  const int ci = idx[g];
  const float cx = sx[ci], cy = sy[ci], cz = sz[ci];
  const float R2 = 0.04000000059604644775f;      // (float)(0.2*0.2)
  const u64 ltmask = (lane == 0) ? 0ull : (~0ull >> (64 - lane));
  int base = 0;
  for (int i = 0; i < NPC/64; ++i) {
    int j = (i << 6) + lane;
    float dx = __fsub_rn(cx, sx[j]);
    float dy = __fsub_rn(cy, sy[j]);
    float dz = __fsub_rn(cz, sz[j]);
    float d2 = __fadd_rn(__fadd_rn(__fmul_rn(dx,dx), __fmul_rn(dy,dy)), __fmul_rn(dz,dz));
    bool in = d2 <= R2;
    u64 mk = __ballot(in);
    if (in) {
      int slot = base + (int)__popcll(mk & ltmask);
      if (slot < CAP)
        cand[wv][slot] = ((u64)__float_as_uint(d2) << 32) | (u32)j;
    }
    base += (int)__popcll(mk);
  }
  int cnt = base < CAP ? base : CAP;
  u64 mykey[7];
  int myrank[7];
#pragma unroll
  for (int u = 0; u < 7; ++u) {
    int s = lane + (u << 6);
    mykey[u] = (s < cnt) ? cand[wv][s] : ~0ull;
    myrank[u] = 0;
  }
  for (int jj = 0; jj < cnt; ++jj) {
    u64 kj = cand[wv][jj];
#pragma unroll
    for (int u = 0; u < 7; ++u) myrank[u] += (kj < mykey[u]) ? 1 : 0;
  }
#pragma unroll
  for (int u = 0; u < 7; ++u) {
    int s = lane + (u << 6);
    if (s < cnt && myrank[u] < KNB)
      nbr[(size_t)g*KNB + myrank[u]] = cloud*NPC + (int)(mykey[u] & 0xffffffffull);
  }
  if (lane == 0) nvalid[g] = cnt < KNB ? cnt : KNB;
}

// ---------------------------------------------------------------- PointNetConv (one block per centroid)
__global__ __launch_bounds__(256)
void conv_kernel(const float* __restrict__ pos, const int* __restrict__ idx,
                 const int* __restrict__ nbr, const int* __restrict__ nvalid,
                 const u16* __restrict__ y, const u16* __restrict__ w2t,
                 const float* __restrict__ w1, const float* __restrict__ b1,
                 const float* __restrict__ b2, float* __restrict__ out) {
  const int bid = blockIdx.x;
  const int g = (bid & 7) * 2048 + (bid >> 3);   // bijective XCD swizzle (16384 = 8*2048)
  const int cloud = g >> 10;
  __shared__ u16 YH[64][72];     // y rows, then relu'd H1 in-place (same-thread RMW)
  __shared__ u16 WT[128][72];    // W2^T bf16
  __shared__ float rel[64][3];
  __shared__ int nbs[64];
  __shared__ float w1p[192];
  __shared__ float b1s[64];
  const int t = threadIdx.x;
  const int nv = nvalid[g];
  if (t < 64) nbs[t] = (t < nv) ? nbr[(size_t)g*KNB + t] : -1;
  if (t < 192) w1p[t] = w1[64*64 + t];
  else         b1s[t - 192] = b1[t - 192];
  __syncthreads();
  if (t < 64) {
    int ci = cloud*NPC + idx[g];
    float cxx = pos[3*ci], cyy = pos[3*ci+1], czz = pos[3*ci+2];
    int j = nbs[t];
    float r0 = 0.f, r1 = 0.f, r2 = 0.f;
    if (t < nv && j >= 0) {
      r0 = pos[3*j]   - cxx;
      r1 = pos[3*j+1] - cyy;
      r2 = pos[3*j+2] - czz;
    }
    rel[t][0] = r0; rel[t][1] = r1; rel[t][2] = r2;
  }
  {
    int row = t >> 2, part = t & 3;
    int j = nbs[row];
    uint4 v0 = make_uint4(0,0,0,0), v1 = make_uint4(0,0,0,0);
    if (row < nv && j >= 0) {
      const uint4* src = (const uint4*)(y + (size_t)j*64);
      v0 = src[part*2]; v1 = src[part*2 + 1];
    }
    *(uint4*)&YH[row][part*16]     = v0;
    *(uint4*)&YH[row][part*16 + 8] = v1;
  }
#pragma unroll
  for (int k = 0; k < 4; ++k) {
    int l = t + 256*k;             // 1024 uint4 total
    int row = l >> 3, part = l & 7;
    *(uint4*)&WT[row][part*8] = ((const uint4*)w2t)[l];
  }
  __syncthreads();
  {
    int s = t >> 2, c0 = (t & 3) << 4;
    float rx = rel[s][0], ry = rel[s][1], rz = rel[s][2];
#pragma unroll
    for (int c = 0; c < 16; ++c) {
      int cc = c0 + c;
      float v = bf2f(YH[s][cc]) + rx*w1p[cc] + ry*w1p[64+cc] + rz*w1p[128+cc] + b1s[cc];
      v = fmaxf(v, 0.f);
      YH[s][cc] = f2bf(v);
    }
  }
  __syncthreads();
  const int wv = t >> 6, lane = t & 63;
  const int arow = lane & 15, agrp = lane >> 4;
  const int col0 = wv << 5;
  f32x4 acc[4][2];
#pragma unroll
  for (int mt = 0; mt < 4; ++mt)
#pragma unroll
    for (int nt = 0; nt < 2; ++nt) {
      f32x4 z = {0.f, 0.f, 0.f, 0.f};
      acc[mt][nt] = z;
    }
#pragma unroll
  for (int kk = 0; kk < 2; ++kk) {
    short8 a[4], bm[2];
#pragma unroll
    for (int mt = 0; mt < 4; ++mt)
      a[mt] = *(const short8*)&YH[mt*16 + arow][kk*32 + agrp*8];
#pragma unroll
    for (int nt = 0; nt < 2; ++nt)
      bm[nt] = *(const short8*)&WT[col0 + nt*16 + arow][kk*32 + agrp*8];
#pragma unroll
    for (int mt = 0; mt < 4; ++mt)
#pragma unroll
      for (int nt = 0; nt < 2; ++nt)
        acc[mt][nt] = __builtin_amdgcn_mfma_f32_16x16x32_bf16(a[mt], bm[nt], acc[mt][nt], 0, 0, 0);
  }
  float p0 = -__builtin_inff(), p1 = -__builtin_inff();
#pragma unroll
  for (int mt = 0; mt < 4; ++mt) {
#pragma unroll
    for (int r = 0; r < 4; ++r) {
      int slot = mt*16 + agrp*4 + r;
      if (slot < nv) {
        p0 = fmaxf(p0, acc[mt][0][r]);
        p1 = fmaxf(p1, acc[mt][1][r]);
      }
    }
  }
  p0 = fmaxf(p0, __shfl_xor(p0, 16, 64));
  p0 = fmaxf(p0, __shfl_xor(p0, 32, 64));
  p1 = fmaxf(p1, __shfl_xor(p1, 16, 64));
  p1 = fmaxf(p1, __shfl_xor(p1, 32, 64));
  if (lane < 16) {
    int c = col0 + lane;
    out[(size_t)g*128 + c]      = (nv > 0) ? p0 + b2[c]      : 0.f;
    out[(size_t)g*128 + c + 16] = (nv > 0) ? p1 + b2[c + 16] : 0.f;
  }
}

// ---------------------------------------------------------------- launch
extern "C" void kernel_launch(void* const* d_in, const int* in_sizes, int n_in,
                              void* d_out, int out_size, void* d_ws, size_t ws_size,
                              hipStream_t stream) {
  const float* x   = (const float*)d_in[0];
  const float* pos = (const float*)d_in[1];
  // d_in[2] (batch) unused: layout is known (repeat arange(16), 4096 each)
  const float* W1  = (const float*)d_in[3];
  const float* b1  = (const float*)d_in[4];
  const float* W2  = (const float*)d_in[5];
  const float* b2  = (const float*)d_in[6];

  float* out       = (float*)d_out;                    // [16384,128]
  float* pos_out   = out + (size_t)NB*MPC*128;         // [16384,3]
  float* batch_out = pos_out + (size_t)NB*MPC*3;       // [16384] (written as floats)

  char* ws = (char*)d_ws;
  int* idx    = (int*)(ws);                                    // 16384 * 4   = 64 KB
  int* nvalid = (int*)(ws + 65536);                            // 16384 * 4   = 64 KB
  int* nbr    = (int*)(ws + 131072);                           // 16384*64*4  = 4 MB
  u16* w2t    = (u16*)(ws + 131072 + 4194304);                 // 128*64*2    = 16 KB
  u16* y      = (u16*)(ws + 131072 + 4194304 + 16384);         // 65536*64*2  = 8 MB (16B aligned)

  fps_kernel <<<NB,    512,  0, stream>>>(pos, idx, pos_out, batch_out);
  y_kernel   <<<1024,  256,  0, stream>>>(x, W1, y);
  w2t_kernel <<<32,    256,  0, stream>>>(W2, w2t);
  nbr_kernel <<<4096,  256,  0, stream>>>(pos, idx, nbr, nvalid);
  conv_kernel<<<16384, 256,  0, stream>>>(pos, idx, nbr, nvalid, y, w2t, W1, b1, b2, out);
}

// Round 8
// 912.683 us; speedup vs baseline: 1.3155x; 1.3155x over previous
//
#include <hip/hip_runtime.h>

#define NB   16
#define NPC  4096
#define MPC  1024
#define KNB  64
#define FIN  64
#define CAP  448   // candidate capacity per centroid (mean ~137, +26 sigma)

typedef unsigned short u16;
typedef unsigned int   u32;
typedef unsigned long long u64;
typedef __attribute__((ext_vector_type(8))) short short8;
typedef __attribute__((ext_vector_type(4))) float f32x4;

__device__ __forceinline__ u16 f2bf(float f) {
  u32 u = __float_as_uint(f);
  u = u + 0x7fffu + ((u >> 16) & 1u);
  return (u16)(u >> 16);
}
__device__ __forceinline__ float bf2f(u16 b) {
  return __uint_as_float(((u32)b) << 16);
}

// ---- DPP wave reduces (VALU pipe). Canonical 6-stage chain; result lane 63.
// bound_ctrl=false => masked/invalid lanes keep old; compiler inserts the
// mandatory DPP hazard waits (raw asm version faulted in R2).
__device__ __forceinline__ u32 wave_max_u32(u32 x) {
  u32 t;
  t = (u32)__builtin_amdgcn_update_dpp((int)x, (int)x, 0x111, 0xf, 0xf, false); x = x > t ? x : t;
  t = (u32)__builtin_amdgcn_update_dpp((int)x, (int)x, 0x112, 0xf, 0xf, false); x = x > t ? x : t;
  t = (u32)__builtin_amdgcn_update_dpp((int)x, (int)x, 0x114, 0xf, 0xf, false); x = x > t ? x : t;
  t = (u32)__builtin_amdgcn_update_dpp((int)x, (int)x, 0x118, 0xf, 0xf, false); x = x > t ? x : t;
  t = (u32)__builtin_amdgcn_update_dpp((int)x, (int)x, 0x142, 0xa, 0xf, false); x = x > t ? x : t;
  t = (u32)__builtin_amdgcn_update_dpp((int)x, (int)x, 0x143, 0xc, 0xf, false); x = x > t ? x : t;
  return x;
}
__device__ __forceinline__ u32 wave_min_u32(u32 x) {
  u32 t;
  t = (u32)__builtin_amdgcn_update_dpp((int)x, (int)x, 0x111, 0xf, 0xf, false); x = x < t ? x : t;
  t = (u32)__builtin_amdgcn_update_dpp((int)x, (int)x, 0x112, 0xf, 0xf, false); x = x < t ? x : t;
  t = (u32)__builtin_amdgcn_update_dpp((int)x, (int)x, 0x114, 0xf, 0xf, false); x = x < t ? x : t;
  t = (u32)__builtin_amdgcn_update_dpp((int)x, (int)x, 0x118, 0xf, 0xf, false); x = x < t ? x : t;
  t = (u32)__builtin_amdgcn_update_dpp((int)x, (int)x, 0x142, 0xa, 0xf, false); x = x < t ? x : t;
  t = (u32)__builtin_amdgcn_update_dpp((int)x, (int)x, 0x143, 0xc, 0xf, false); x = x < t ? x : t;
  return x;
}

struct FpsLDS {
  float sx[NPC], sy[NPC], sz[NPC];
  u64 swave[2][8];
  int sidx[MPC];
};
struct YLDS { float xs[64][68]; float ws[64][68]; };
union FusedLDS { FpsLDS f; YLDS g; };

// ---------------------------------------------------------------- fused FPS + y + w2t
// Blocks 0..15: FPS (R3-proven dense structure, 512 thr = 8 waves).
//   Key change vs R3: NO global stores inside the 1023-step loop — idx
//   goes to LDS (one ds_write by t0), outputs flushed at the end via
//   gather pos_out[i] = sx[sidx[i]] (exact original bits). This keeps
//   every per-step __syncthreads' implicit vmcnt(0) drain trivial.
// Blocks 16..1039: y = x @ W1[:64] (f32 accum k=0..63 order, bf16 store).
// Block 1040: W2 -> bf16 transposed. These overlap fps' idle 240 CUs.
__global__ __launch_bounds__(512)
void fused_kernel(const float* __restrict__ pos, const float* __restrict__ x,
                  const float* __restrict__ w1, const float* __restrict__ w2,
                  int* __restrict__ idx_out, float* __restrict__ pos_out,
                  float* __restrict__ batch_out, u16* __restrict__ y,
                  u16* __restrict__ w2t) {
  __shared__ FusedLDS L;
  const int bid = blockIdx.x;
  const int t = threadIdx.x;
  if (bid < NB) {
    // ---------------- FPS (exact R3 math: __f*_rn, (x2+y2)+z2, fminf;
    // argmax first-index tie-break via value-max then index-min reduce)
    const int b = bid;
    const float* P = pos + (size_t)b * NPC * 3;
    for (int i = t; i < NPC; i += 512) {
      L.f.sx[i] = P[3*i+0]; L.f.sy[i] = P[3*i+1]; L.f.sz[i] = P[3*i+2];
    }
    for (int i = t; i < MPC; i += 512) batch_out[b*MPC + i] = (float)b;
    if (t == 0) L.f.sidx[0] = 0;
    __syncthreads();
    float px[8], py[8], pz[8], mind[8];
#pragma unroll
    for (int r = 0; r < 8; ++r) {
      int i = t + (r << 9);
      px[r] = L.f.sx[i]; py[r] = L.f.sy[i]; pz[r] = L.f.sz[i];
      mind[r] = __builtin_inff();
    }
    int last = 0;
    for (int m = 1; m < MPC; ++m) {
      float cx = L.f.sx[last], cy = L.f.sy[last], cz = L.f.sz[last];
      u32 vmax = 0;
#pragma unroll
      for (int r = 0; r < 8; ++r) {
        float dx = __fsub_rn(px[r], cx);
        float dy = __fsub_rn(py[r], cy);
        float dz = __fsub_rn(pz[r], cz);
        float d2 = __fadd_rn(__fadd_rn(__fmul_rn(dx,dx), __fmul_rn(dy,dy)), __fmul_rn(dz,dz));
        mind[r] = fminf(mind[r], d2);
        u32 bits = __float_as_uint(mind[r]);
        vmax = bits > vmax ? bits : vmax;
      }
      vmax = wave_max_u32(vmax);
      u32 V = (u32)__builtin_amdgcn_readlane((int)vmax, 63);
      u32 cand = 0xffffffffu;
#pragma unroll
      for (int r = 7; r >= 0; --r)
        cand = (__float_as_uint(mind[r]) == V) ? (u32)(t + (r << 9)) : cand;
      cand = wave_min_u32(cand);
      if ((t & 63) == 63) L.f.swave[m & 1][t >> 6] = ((u64)V << 32) | (u32)(~cand);
      __syncthreads();   // single barrier per step (parity double-buffer)
      u64 w = L.f.swave[m & 1][0];
#pragma unroll
      for (int q = 1; q < 8; ++q) {
        u64 o = L.f.swave[m & 1][q];
        w = o > w ? o : w;
      }
      last = (int)(~(u32)w);
      if (t == 0) L.f.sidx[m] = last;   // LDS only — no vmem in the loop
    }
    __syncthreads();
    // flush: idx + gathered coords (exact original bits)
    for (int i = t; i < MPC; i += 512) {
      int ii = L.f.sidx[i];
      idx_out[b*MPC + i] = ii;
      size_t po = ((size_t)b*MPC + i)*3;
      pos_out[po+0] = L.f.sx[ii];
      pos_out[po+1] = L.f.sy[ii];
      pos_out[po+2] = L.f.sz[ii];
    }
  } else if (bid < NB + 1024) {
    // ---------------- y = x @ W1[:64], 512 threads per 64-row tile
    const size_t row0 = (size_t)(bid - NB) * 64;
#pragma unroll
    for (int k = 0; k < 2; ++k) {
      int l4 = t + 512*k;              // 0..1023 float4 index
      int r = l4 >> 4, c4 = l4 & 15;
      *(float4*)&L.g.xs[r][c4*4] = *(const float4*)&x[(row0 + r)*64 + c4*4];
      *(float4*)&L.g.ws[r][c4*4] = *(const float4*)&w1[r*64 + c4*4];
    }
    __syncthreads();
    const int r = t >> 3, c0 = (t & 7) << 3;
    float acc[8];
#pragma unroll
    for (int i = 0; i < 8; ++i) acc[i] = 0.f;
    for (int k = 0; k < 64; ++k) {
      float a = L.g.xs[r][k];
      float4 w0 = *(const float4*)&L.g.ws[k][c0];
      float4 w1v = *(const float4*)&L.g.ws[k][c0 + 4];
      acc[0] += a * w0.x; acc[1] += a * w0.y; acc[2] += a * w0.z; acc[3] += a * w0.w;
      acc[4] += a * w1v.x; acc[5] += a * w1v.y; acc[6] += a * w1v.z; acc[7] += a * w1v.w;
    }
    u32 u[4];
#pragma unroll
    for (int i = 0; i < 4; ++i)
      u[i] = (u32)f2bf(acc[2*i]) | ((u32)f2bf(acc[2*i+1]) << 16);
    *(uint4*)(y + ((row0 + r)*64 + c0)) = make_uint4(u[0], u[1], u[2], u[3]);
  } else {
    // ---------------- W2 -> bf16 transposed [128][64]
    for (int i = t; i < 64*128; i += 512) {
      int k = i >> 7, c = i & 127;
      w2t[c*64 + k] = f2bf(w2[i]);
    }
  }
}

// ---------------------------------------------------------------- radius + top-64 neighbors
// Replicates lax.top_k(-d2,64) stability via key=(d2_bits, idx) ranking.
__global__ __launch_bounds__(256)
void nbr_kernel(const float* __restrict__ pos, const int* __restrict__ idx,
                int* __restrict__ nbr, int* __restrict__ nvalid) {
  const int bid = blockIdx.x;
  const int sw = (bid & 7) * 512 + (bid >> 3);   // bijective XCD swizzle (4096 = 8*512)
  const int cloud = sw >> 8;
  const int mbase = (sw & 255) << 2;
  __shared__ float sx[NPC], sy[NPC], sz[NPC];
  __shared__ u64 cand[4][CAP];
  const float* P = pos + (size_t)cloud * NPC * 3;
  const int t = threadIdx.x;
  for (int i = t; i < NPC; i += 256) { sx[i]=P[3*i]; sy[i]=P[3*i+1]; sz[i]=P[3*i+2]; }
  __syncthreads();
  const int wv = t >> 6, lane = t & 63;
  const int m = mbase + wv;
  const int g = cloud * MPC + m;
  const int ci = idx[g];
  const float cx = sx[ci], cy = sy[ci], cz = sz[ci];
  const float R2 = 0.04000000059604644775f;      // (float)(0.2*0.2)
  const u64 ltmask = (lane == 0) ? 0ull : (~0ull >> (64 - lane));
  int base = 0;
  for (int i = 0; i < NPC/64; ++i) {
    int j = (i << 6) + lane;
    float dx = __fsub_rn(cx, sx[j]);
    float dy = __fsub_rn(cy, sy[j]);
    float dz = __fsub_rn(cz, sz[j]);
    float d2 = __fadd_rn(__fadd_rn(__fmul_rn(dx,dx), __fmul_rn(dy,dy)), __fmul_rn(dz,dz));
    bool in = d2 <= R2;
    u64 mk = __ballot(in);
    if (in) {
      int slot = base + (int)__popcll(mk & ltmask);
      if (slot < CAP)
        cand[wv][slot] = ((u64)__float_as_uint(d2) << 32) | (u32)j;
    }
    base += (int)__popcll(mk);
  }
  int cnt = base < CAP ? base : CAP;
  u64 mykey[7];
  int myrank[7];
#pragma unroll
  for (int u = 0; u < 7; ++u) {
    int s = lane + (u << 6);
    mykey[u] = (s < cnt) ? cand[wv][s] : ~0ull;
    myrank[u] = 0;
  }
  for (int jj = 0; jj < cnt; ++jj) {
    u64 kj = cand[wv][jj];
#pragma unroll
    for (int u = 0; u < 7; ++u) myrank[u] += (kj < mykey[u]) ? 1 : 0;
  }
#pragma unroll
  for (int u = 0; u < 7; ++u) {
    int s = lane + (u << 6);
    if (s < cnt && myrank[u] < KNB)
      nbr[(size_t)g*KNB + myrank[u]] = cloud*NPC + (int)(mykey[u] & 0xffffffffull);
  }
  if (lane == 0) nvalid[g] = cnt < KNB ? cnt : KNB;
}

// ---------------------------------------------------------------- PointNetConv (one block per centroid)
__global__ __launch_bounds__(256)
void conv_kernel(const float* __restrict__ pos, const int* __restrict__ idx,
                 const int* __restrict__ nbr, const int* __restrict__ nvalid,
                 const u16* __restrict__ y, const u16* __restrict__ w2t,
                 const float* __restrict__ w1, const float* __restrict__ b1,
                 const float* __restrict__ b2, float* __restrict__ out) {
  const int bid = blockIdx.x;
  const int g = (bid & 7) * 2048 + (bid >> 3);   // bijective XCD swizzle (16384 = 8*2048)
  const int cloud = g >> 10;
  __shared__ u16 YH[64][72];     // y rows, then relu'd H1 in-place (same-thread RMW)
  __shared__ u16 WT[128][72];    // W2^T bf16
  __shared__ float rel[64][3];
  __shared__ int nbs[64];
  __shared__ float w1p[192];
  __shared__ float b1s[64];
  const int t = threadIdx.x;
  const int nv = nvalid[g];
  if (t < 64) nbs[t] = (t < nv) ? nbr[(size_t)g*KNB + t] : -1;
  if (t < 192) w1p[t] = w1[64*64 + t];
  else         b1s[t - 192] = b1[t - 192];
  __syncthreads();
  if (t < 64) {
    int ci = cloud*NPC + idx[g];
    float cxx = pos[3*ci], cyy = pos[3*ci+1], czz = pos[3*ci+2];
    int j = nbs[t];
    float r0 = 0.f, r1 = 0.f, r2 = 0.f;
    if (t < nv && j >= 0) {
      r0 = pos[3*j]   - cxx;
      r1 = pos[3*j+1] - cyy;
      r2 = pos[3*j+2] - czz;
    }
    rel[t][0] = r0; rel[t][1] = r1; rel[t][2] = r2;
  }
  {
    int row = t >> 2, part = t & 3;
    int j = nbs[row];
    uint4 v0 = make_uint4(0,0,0,0), v1 = make_uint4(0,0,0,0);
    if (row < nv && j >= 0) {
      const uint4* src = (const uint4*)(y + (size_t)j*64);
      v0 = src[part*2]; v1 = src[part*2 + 1];
    }
    *(uint4*)&YH[row][part*16]     = v0;
    *(uint4*)&YH[row][part*16 + 8] = v1;
  }
#pragma unroll
  for (int k = 0; k < 4; ++k) {
    int l = t + 256*k;             // 1024 uint4 total
    int row = l >> 3, part = l & 7;
    *(uint4*)&WT[row][part*8] = ((const uint4*)w2t)[l];
  }
  __syncthreads();
  {
    int s = t >> 2, c0 = (t & 3) << 4;
    float rx = rel[s][0], ry = rel[s][1], rz = rel[s][2];
#pragma unroll
    for (int c = 0; c < 16; ++c) {
      int cc = c0 + c;
      float v = bf2f(YH[s][cc]) + rx*w1p[cc] + ry*w1p[64+cc] + rz*w1p[128+cc] + b1s[cc];
      v = fmaxf(v, 0.f);
      YH[s][cc] = f2bf(v);
    }
  }
  __syncthreads();
  const int wv = t >> 6, lane = t & 63;
  const int arow = lane & 15, agrp = lane >> 4;
  const int col0 = wv << 5;
  f32x4 acc[4][2];
#pragma unroll
  for (int mt = 0; mt < 4; ++mt)
#pragma unroll
    for (int nt = 0; nt < 2; ++nt) {
      f32x4 z = {0.f, 0.f, 0.f, 0.f};
      acc[mt][nt] = z;
    }
#pragma unroll
  for (int kk = 0; kk < 2; ++kk) {
    short8 a[4], bm[2];
#pragma unroll
    for (int mt = 0; mt < 4; ++mt)
      a[mt] = *(const short8*)&YH[mt*16 + arow][kk*32 + agrp*8];
#pragma unroll
    for (int nt = 0; nt < 2; ++nt)
      bm[nt] = *(const short8*)&WT[col0 + nt*16 + arow][kk*32 + agrp*8];
#pragma unroll
    for (int mt = 0; mt < 4; ++mt)
#pragma unroll
      for (int nt = 0; nt < 2; ++nt)
        acc[mt][nt] = __builtin_amdgcn_mfma_f32_16x16x32_bf16(a[mt], bm[nt], acc[mt][nt], 0, 0, 0);
  }
  float p0 = -__builtin_inff(), p1 = -__builtin_inff();
#pragma unroll
  for (int mt = 0; mt < 4; ++mt) {
#pragma unroll
    for (int r = 0; r < 4; ++r) {
      int slot = mt*16 + agrp*4 + r;
      if (slot < nv) {
        p0 = fmaxf(p0, acc[mt][0][r]);
        p1 = fmaxf(p1, acc[mt][1][r]);
      }
    }
  }
  p0 = fmaxf(p0, __shfl_xor(p0, 16, 64));
  p0 = fmaxf(p0, __shfl_xor(p0, 32, 64));
  p1 = fmaxf(p1, __shfl_xor(p1, 16, 64));
  p1 = fmaxf(p1, __shfl_xor(p1, 32, 64));
  if (lane < 16) {
    int c = col0 + lane;
    out[(size_t)g*128 + c]      = (nv > 0) ? p0 + b2[c]      : 0.f;
    out[(size_t)g*128 + c + 16] = (nv > 0) ? p1 + b2[c + 16] : 0.f;
  }
}

// ---------------------------------------------------------------- launch
extern "C" void kernel_launch(void* const* d_in, const int* in_sizes, int n_in,
                              void* d_out, int out_size, void* d_ws, size_t ws_size,
                              hipStream_t stream) {
  const float* x   = (const float*)d_in[0];
  const float* pos = (const float*)d_in[1];
  // d_in[2] (batch) unused: layout is known (repeat arange(16), 4096 each)
  const float* W1  = (const float*)d_in[3];
  const float* b1  = (const float*)d_in[4];
  const float* W2  = (const float*)d_in[5];
  const float* b2  = (const float*)d_in[6];

  float* out       = (float*)d_out;                    // [16384,128]
  float* pos_out   = out + (size_t)NB*MPC*128;         // [16384,3]
  float* batch_out = pos_out + (size_t)NB*MPC*3;       // [16384] (written as floats)

  char* ws = (char*)d_ws;
  int* idx    = (int*)(ws);                                    // 16384 * 4   = 64 KB
  int* nvalid = (int*)(ws + 65536);                            // 16384 * 4   = 64 KB
  int* nbr    = (int*)(ws + 131072);                           // 16384*64*4  = 4 MB
  u16* w2t    = (u16*)(ws + 131072 + 4194304);                 // 128*64*2    = 16 KB
  u16* y      = (u16*)(ws + 131072 + 4194304 + 16384);         // 65536*64*2  = 8 MB (16B aligned)

  fused_kernel<<<NB + 1024 + 1, 512, 0, stream>>>(pos, x, W1, W2, idx, pos_out,
                                                  batch_out, y, w2t);
  nbr_kernel <<<4096,  256,  0, stream>>>(pos, idx, nbr, nvalid);
  conv_kernel<<<16384, 256,  0, stream>>>(pos, idx, nbr, nvalid, y, w2t, W1, b1, b2, out);
}

// Round 9
// 893.596 us; speedup vs baseline: 1.3436x; 1.0214x over previous
//
#include <hip/hip_runtime.h>

#define NB   16
#define NPC  4096
#define MPC  1024
#define KNB  64
#define FIN  64
#define CAP  448   // candidate capacity per centroid (mean ~137, +26 sigma)

typedef unsigned short u16;
typedef unsigned int   u32;
typedef unsigned long long u64;
typedef __attribute__((ext_vector_type(8))) short short8;
typedef __attribute__((ext_vector_type(4))) float f32x4;

__device__ __forceinline__ u16 f2bf(float f) {
  u32 u = __float_as_uint(f);
  u = u + 0x7fffu + ((u >> 16) & 1u);
  return (u16)(u >> 16);
}
__device__ __forceinline__ float bf2f(u16 b) {
  return __uint_as_float(((u32)b) << 16);
}

// ---- DPP wave reduces (VALU pipe). bound_ctrl=false => invalid/masked
// lanes keep old; compiler inserts mandatory DPP hazard waits (raw asm
// faulted in R2). row_shr moves values toward HIGHER lanes (R3-verified).
#define DPP64_MAX(best, ctrl, rmask) do { \
  u32 _lo = (u32)(best), _hi = (u32)((best) >> 32); \
  u32 _olo = (u32)__builtin_amdgcn_update_dpp((int)_lo, (int)_lo, (ctrl), (rmask), 0xf, false); \
  u32 _ohi = (u32)__builtin_amdgcn_update_dpp((int)_hi, (int)_hi, (ctrl), (rmask), 0xf, false); \
  u64 _o = ((u64)_ohi << 32) | _olo; \
  (best) = _o > (best) ? _o : (best); \
} while (0)

__device__ __forceinline__ u32 wave_max_u32(u32 x) {
  u32 t;
  t = (u32)__builtin_amdgcn_update_dpp((int)x, (int)x, 0x111, 0xf, 0xf, false); x = x > t ? x : t;
  t = (u32)__builtin_amdgcn_update_dpp((int)x, (int)x, 0x112, 0xf, 0xf, false); x = x > t ? x : t;
  t = (u32)__builtin_amdgcn_update_dpp((int)x, (int)x, 0x114, 0xf, 0xf, false); x = x > t ? x : t;
  t = (u32)__builtin_amdgcn_update_dpp((int)x, (int)x, 0x118, 0xf, 0xf, false); x = x > t ? x : t;
  t = (u32)__builtin_amdgcn_update_dpp((int)x, (int)x, 0x142, 0xa, 0xf, false); x = x > t ? x : t;
  t = (u32)__builtin_amdgcn_update_dpp((int)x, (int)x, 0x143, 0xc, 0xf, false); x = x > t ? x : t;
  return x;
}
__device__ __forceinline__ u32 wave_min_u32(u32 x) {
  u32 t;
  t = (u32)__builtin_amdgcn_update_dpp((int)x, (int)x, 0x111, 0xf, 0xf, false); x = x < t ? x : t;
  t = (u32)__builtin_amdgcn_update_dpp((int)x, (int)x, 0x112, 0xf, 0xf, false); x = x < t ? x : t;
  t = (u32)__builtin_amdgcn_update_dpp((int)x, (int)x, 0x114, 0xf, 0xf, false); x = x < t ? x : t;
  t = (u32)__builtin_amdgcn_update_dpp((int)x, (int)x, 0x118, 0xf, 0xf, false); x = x < t ? x : t;
  t = (u32)__builtin_amdgcn_update_dpp((int)x, (int)x, 0x142, 0xa, 0xf, false); x = x < t ? x : t;
  t = (u32)__builtin_amdgcn_update_dpp((int)x, (int)x, 0x143, 0xc, 0xf, false); x = x < t ? x : t;
  return x;
}

struct FpsLDS {
  float4 sxyz[NPC];     // packed coords: 1 ds_read_b128 per centroid fetch
  u64 swave[2][8];
  int sidx[MPC];
};
struct YLDS { float xs[64][68]; float ws[64][68]; };
union FusedLDS { FpsLDS f; YLDS g; char pad[86016]; };  // 84KB => 1 block/CU
                                                        // (fps CUs exclusive)

// ---------------------------------------------------------------- fused FPS + y + w2t
// Blocks 0..15: FPS, R3-proven math; per-step DS instructions cut 12 -> 3:
//   1 b128 coord fetch + 1 b64 key write (lane 63) + 1 b64 lane-parallel
//   scan read (lanes 0-7) + 3-stage DPP u64 max + 1 readlane.
// Blocks 16..1039: y = x @ W1[:64] (f32 accum k-order, bf16 store).
// Block 1040: W2 -> bf16 transposed. Overlap fps' idle CUs (1 block/CU).
__global__ __launch_bounds__(512)
void fused_kernel(const float* __restrict__ pos, const float* __restrict__ x,
                  const float* __restrict__ w1, const float* __restrict__ w2,
                  int* __restrict__ idx_out, float* __restrict__ pos_out,
                  float* __restrict__ batch_out, u16* __restrict__ y,
                  u16* __restrict__ w2t) {
  __shared__ FusedLDS L;
  const int bid = blockIdx.x;
  const int t = threadIdx.x;
  if (bid < NB) {
    const int b = bid;
    const int w = t >> 6, lane = t & 63;
    const float* P = pos + (size_t)b * NPC * 3;
    for (int i = t; i < NPC; i += 512)
      L.f.sxyz[i] = make_float4(P[3*i+0], P[3*i+1], P[3*i+2], 0.f);
    for (int i = t; i < MPC; i += 512) batch_out[b*MPC + i] = (float)b;
    if (t == 0) L.f.sidx[0] = 0;
    __syncthreads();
    float px[8], py[8], pz[8], mind[8];
#pragma unroll
    for (int r = 0; r < 8; ++r) {
      float4 p = L.f.sxyz[t + (r << 9)];
      px[r] = p.x; py[r] = p.y; pz[r] = p.z;
      mind[r] = __builtin_inff();
    }
    int last = 0;
    for (int m = 1; m < MPC; ++m) {
      float4 c = L.f.sxyz[last];           // 1 ds_read_b128
      u32 vmax = 0;
#pragma unroll
      for (int r = 0; r < 8; ++r) {
        float dx = __fsub_rn(px[r], c.x);
        float dy = __fsub_rn(py[r], c.y);
        float dz = __fsub_rn(pz[r], c.z);
        float d2 = __fadd_rn(__fadd_rn(__fmul_rn(dx,dx), __fmul_rn(dy,dy)), __fmul_rn(dz,dz));
        mind[r] = fminf(mind[r], d2);
        u32 bits = __float_as_uint(mind[r]);
        vmax = bits > vmax ? bits : vmax;
      }
      vmax = wave_max_u32(vmax);
      u32 V = (u32)__builtin_amdgcn_readlane((int)vmax, 63);
      u32 cand = 0xffffffffu;
#pragma unroll
      for (int r = 7; r >= 0; --r)
        cand = (__float_as_uint(mind[r]) == V) ? (u32)(t + (r << 9)) : cand;
      cand = wave_min_u32(cand);
      if (lane == 63) L.f.swave[m & 1][w] = ((u64)V << 32) | (u32)(~cand);
      __syncthreads();   // single barrier per step (parity double-buffer)
      // lane-parallel scan: lanes 0-7 read one wave-key each, 3-stage DPP
      // u64 max (result lane 7), one readlane.
      u64 sv = 0;
      if (lane < 8) sv = L.f.swave[m & 1][lane];
      DPP64_MAX(sv, 0x111, 0xf);
      DPP64_MAX(sv, 0x112, 0xf);
      DPP64_MAX(sv, 0x114, 0xf);
      u32 lo = (u32)__builtin_amdgcn_readlane((int)(u32)sv, 7);
      last = (int)(~lo);
      if (t == 0) L.f.sidx[m] = last;     // LDS only — no vmem in the loop
    }
    __syncthreads();
    // flush: idx + gathered coords (exact original bits)
    for (int i = t; i < MPC; i += 512) {
      int ii = L.f.sidx[i];
      idx_out[b*MPC + i] = ii;
      float4 p = L.f.sxyz[ii];
      size_t po = ((size_t)b*MPC + i)*3;
      pos_out[po+0] = p.x; pos_out[po+1] = p.y; pos_out[po+2] = p.z;
    }
  } else if (bid < NB + 1024) {
    // ---------------- y = x @ W1[:64], 512 threads per 64-row tile
    const size_t row0 = (size_t)(bid - NB) * 64;
#pragma unroll
    for (int k = 0; k < 2; ++k) {
      int l4 = t + 512*k;              // 0..1023 float4 index
      int r = l4 >> 4, c4 = l4 & 15;
      *(float4*)&L.g.xs[r][c4*4] = *(const float4*)&x[(row0 + r)*64 + c4*4];
      *(float4*)&L.g.ws[r][c4*4] = *(const float4*)&w1[r*64 + c4*4];
    }
    __syncthreads();
    const int r = t >> 3, c0 = (t & 7) << 3;
    float acc[8];
#pragma unroll
    for (int i = 0; i < 8; ++i) acc[i] = 0.f;
    for (int k = 0; k < 64; ++k) {
      float a = L.g.xs[r][k];
      float4 w0 = *(const float4*)&L.g.ws[k][c0];
      float4 w1v = *(const float4*)&L.g.ws[k][c0 + 4];
      acc[0] += a * w0.x; acc[1] += a * w0.y; acc[2] += a * w0.z; acc[3] += a * w0.w;
      acc[4] += a * w1v.x; acc[5] += a * w1v.y; acc[6] += a * w1v.z; acc[7] += a * w1v.w;
    }
    u32 u[4];
#pragma unroll
    for (int i = 0; i < 4; ++i)
      u[i] = (u32)f2bf(acc[2*i]) | ((u32)f2bf(acc[2*i+1]) << 16);
    *(uint4*)(y + ((row0 + r)*64 + c0)) = make_uint4(u[0], u[1], u[2], u[3]);
  } else {
    // ---------------- W2 -> bf16 transposed [128][64]
    for (int i = t; i < 64*128; i += 512) {
      int k = i >> 7, c = i & 127;
      w2t[c*64 + k] = f2bf(w2[i]);
    }
  }
}

// ---------------------------------------------------------------- radius + top-64 neighbors
// Replicates lax.top_k(-d2,64) stability via key=(d2_bits, idx) ranking.
__global__ __launch_bounds__(256)
void nbr_kernel(const float* __restrict__ pos, const int* __restrict__ idx,
                int* __restrict__ nbr, int* __restrict__ nvalid) {
  const int bid = blockIdx.x;
  const int sw = (bid & 7) * 512 + (bid >> 3);   // bijective XCD swizzle (4096 = 8*512)
  const int cloud = sw >> 8;
  const int mbase = (sw & 255) << 2;
  __shared__ float sx[NPC], sy[NPC], sz[NPC];
  __shared__ u64 cand[4][CAP];
  const float* P = pos + (size_t)cloud * NPC * 3;
  const int t = threadIdx.x;
  for (int i = t; i < NPC; i += 256) { sx[i]=P[3*i]; sy[i]=P[3*i+1]; sz[i]=P[3*i+2]; }
  __syncthreads();
  const int wv = t >> 6, lane = t & 63;
  const int m = mbase + wv;
  const int g = cloud * MPC + m;
  const int ci = idx[g];
  const float cx = sx[ci], cy = sy[ci], cz = sz[ci];
  const float R2 = 0.04000000059604644775f;      // (float)(0.2*0.2)
  const u64 ltmask = (lane == 0) ? 0ull : (~0ull >> (64 - lane));
  int base = 0;
  for (int i = 0; i < NPC/64; ++i) {
    int j = (i << 6) + lane;
    float dx = __fsub_rn(cx, sx[j]);
    float dy = __fsub_rn(cy, sy[j]);
    float dz = __fsub_rn(cz, sz[j]);
    float d2 = __fadd_rn(__fadd_rn(__fmul_rn(dx,dx), __fmul_rn(dy,dy)), __fmul_rn(dz,dz));
    bool in = d2 <= R2;
    u64 mk = __ballot(in);
    if (in) {
      int slot = base + (int)__popcll(mk & ltmask);
      if (slot < CAP)
        cand[wv][slot] = ((u64)__float_as_uint(d2) << 32) | (u32)j;
    }
    base += (int)__popcll(mk);
  }
  int cnt = base < CAP ? base : CAP;
  u64 mykey[7];
  int myrank[7];
#pragma unroll
  for (int u = 0; u < 7; ++u) {
    int s = lane + (u << 6);
    mykey[u] = (s < cnt) ? cand[wv][s] : ~0ull;
    myrank[u] = 0;
  }
  for (int jj = 0; jj < cnt; ++jj) {
    u64 kj = cand[wv][jj];
#pragma unroll
    for (int u = 0; u < 7; ++u) myrank[u] += (kj < mykey[u]) ? 1 : 0;
  }
#pragma unroll
  for (int u = 0; u < 7; ++u) {
    int s = lane + (u << 6);
    if (s < cnt && myrank[u] < KNB)
      nbr[(size_t)g*KNB + myrank[u]] = cloud*NPC + (int)(mykey[u] & 0xffffffffull);
  }
  if (lane == 0) nvalid[g] = cnt < KNB ? cnt : KNB;
}

// ---------------------------------------------------------------- PointNetConv (one block per centroid)
__global__ __launch_bounds__(256)
void conv_kernel(const float* __restrict__ pos, const int* __restrict__ idx,
                 const int* __restrict__ nbr, const int* __restrict__ nvalid,
                 const u16* __restrict__ y, const u16* __restrict__ w2t,
                 const float* __restrict__ w1, const float* __restrict__ b1,
                 const float* __restrict__ b2, float* __restrict__ out) {
  const int bid = blockIdx.x;
  const int g = (bid & 7) * 2048 + (bid >> 3);   // bijective XCD swizzle (16384 = 8*2048)
  const int cloud = g >> 10;
  __shared__ u16 YH[64][72];     // y rows, then relu'd H1 in-place (same-thread RMW)
  __shared__ u16 WT[128][72];    // W2^T bf16
  __shared__ float rel[64][3];
  __shared__ int nbs[64];
  __shared__ float w1p[192];
  __shared__ float b1s[64];
  const int t = threadIdx.x;
  const int nv = nvalid[g];
  if (t < 64) nbs[t] = (t < nv) ? nbr[(size_t)g*KNB + t] : -1;
  if (t < 192) w1p[t] = w1[64*64 + t];
  else         b1s[t - 192] = b1[t - 192];
  __syncthreads();
  if (t < 64) {
    int ci = cloud*NPC + idx[g];
    float cxx = pos[3*ci], cyy = pos[3*ci+1], czz = pos[3*ci+2];
    int j = nbs[t];
    float r0 = 0.f, r1 = 0.f, r2 = 0.f;
    if (t < nv && j >= 0) {
      r0 = pos[3*j]   - cxx;
      r1 = pos[3*j+1] - cyy;
      r2 = pos[3*j+2] - czz;
    }
    rel[t][0] = r0; rel[t][1] = r1; rel[t][2] = r2;
  }
  {
    int row = t >> 2, part = t & 3;
    int j = nbs[row];
    uint4 v0 = make_uint4(0,0,0,0), v1 = make_uint4(0,0,0,0);
    if (row < nv && j >= 0) {
      const uint4* src = (const uint4*)(y + (size_t)j*64);
      v0 = src[part*2]; v1 = src[part*2 + 1];
    }
    *(uint4*)&YH[row][part*16]     = v0;
    *(uint4*)&YH[row][part*16 + 8] = v1;
  }
#pragma unroll
  for (int k = 0; k < 4; ++k) {
    int l = t + 256*k;             // 1024 uint4 total
    int row = l >> 3, part = l & 7;
    *(uint4*)&WT[row][part*8] = ((const uint4*)w2t)[l];
  }
  __syncthreads();
  {
    int s = t >> 2, c0 = (t & 3) << 4;
    float rx = rel[s][0], ry = rel[s][1], rz = rel[s][2];
#pragma unroll
    for (int c = 0; c < 16; ++c) {
      int cc = c0 + c;
      float v = bf2f(YH[s][cc]) + rx*w1p[cc] + ry*w1p[64+cc] + rz*w1p[128+cc] + b1s[cc];
      v = fmaxf(v, 0.f);
      YH[s][cc] = f2bf(v);
    }
  }
  __syncthreads();
  const int wv = t >> 6, lane = t & 63;
  const int arow = lane & 15, agrp = lane >> 4;
  const int col0 = wv << 5;
  f32x4 acc[4][2];
#pragma unroll
  for (int mt = 0; mt < 4; ++mt)
#pragma unroll
    for (int nt = 0; nt < 2; ++nt) {
      f32x4 z = {0.f, 0.f, 0.f, 0.f};
      acc[mt][nt] = z;
    }
#pragma unroll
  for (int kk = 0; kk < 2; ++kk) {
    short8 a[4], bm[2];
#pragma unroll
    for (int mt = 0; mt < 4; ++mt)
      a[mt] = *(const short8*)&YH[mt*16 + arow][kk*32 + agrp*8];
#pragma unroll
    for (int nt = 0; nt < 2; ++nt)
      bm[nt] = *(const short8*)&WT[col0 + nt*16 + arow][kk*32 + agrp*8];
#pragma unroll
    for (int mt = 0; mt < 4; ++mt)
#pragma unroll
      for (int nt = 0; nt < 2; ++nt)
        acc[mt][nt] = __builtin_amdgcn_mfma_f32_16x16x32_bf16(a[mt], bm[nt], acc[mt][nt], 0, 0, 0);
  }
  float p0 = -__builtin_inff(), p1 = -__builtin_inff();
#pragma unroll
  for (int mt = 0; mt < 4; ++mt) {
#pragma unroll
    for (int r = 0; r < 4; ++r) {
      int slot = mt*16 + agrp*4 + r;
      if (slot < nv) {
        p0 = fmaxf(p0, acc[mt][0][r]);
        p1 = fmaxf(p1, acc[mt][1][r]);
      }
    }
  }
  p0 = fmaxf(p0, __shfl_xor(p0, 16, 64));
  p0 = fmaxf(p0, __shfl_xor(p0, 32, 64));
  p1 = fmaxf(p1, __shfl_xor(p1, 16, 64));
  p1 = fmaxf(p1, __shfl_xor(p1, 32, 64));
  if (lane < 16) {
    int c = col0 + lane;
    out[(size_t)g*128 + c]      = (nv > 0) ? p0 + b2[c]      : 0.f;
    out[(size_t)g*128 + c + 16] = (nv > 0) ? p1 + b2[c + 16] : 0.f;
  }
}

// ---------------------------------------------------------------- launch
extern "C" void kernel_launch(void* const* d_in, const int* in_sizes, int n_in,
                              void* d_out, int out_size, void* d_ws, size_t ws_size,
                              hipStream_t stream) {
  const float* x   = (const float*)d_in[0];
  const float* pos = (const float*)d_in[1];
  // d_in[2] (batch) unused: layout is known (repeat arange(16), 4096 each)
  const float* W1  = (const float*)d_in[3];
  const float* b1  = (const float*)d_in[4];
  const float* W2  = (const float*)d_in[5];
  const float* b2  = (const float*)d_in[6];

  float* out       = (float*)d_out;                    // [16384,128]
  float* pos_out   = out + (size_t)NB*MPC*128;         // [16384,3]
  float* batch_out = pos_out + (size_t)NB*MPC*3;       // [16384] (written as floats)

  char* ws = (char*)d_ws;
  int* idx    = (int*)(ws);                                    // 16384 * 4   = 64 KB
  int* nvalid = (int*)(ws + 65536);                            // 16384 * 4   = 64 KB
  int* nbr    = (int*)(ws + 131072);                           // 16384*64*4  = 4 MB
  u16* w2t    = (u16*)(ws + 131072 + 4194304);                 // 128*64*2    = 16 KB
  u16* y      = (u16*)(ws + 131072 + 4194304 + 16384);         // 65536*64*2  = 8 MB (16B aligned)

  fused_kernel<<<NB + 1024 + 1, 512, 0, stream>>>(pos, x, W1, W2, idx, pos_out,
                                                  batch_out, y, w2t);
  nbr_kernel <<<4096,  256,  0, stream>>>(pos, idx, nbr, nvalid);
  conv_kernel<<<16384, 256,  0, stream>>>(pos, idx, nbr, nvalid, y, w2t, W1, b1, b2, out);
}